// Round 9
// baseline (373.168 us; speedup 1.0000x reference)
//
#include <hip/hip_runtime.h>
#include <math.h>

// MADE autoregressive sampler, incremental-by-degree, v8: wave-autonomous
// dataflow (v7) + block-shared W2 LDS double-buffer (1 barrier/step).
// B=8192, D=64, CTX=256, H=512. Units sorted by degree (mh = h%63+1).
// Lane l owns sorted cols [8l,8l+8) x 2 rows (wave w owns rows 2w,2w+1).
// z broadcast: __shfl. h1/h2 group values: per-wave LDS (program order).
// W2 step-block (9x512 f32, 18KB) staged into LDS dbuf by the whole block,
// flipped by the step-top __syncthreads. W2 rows are XOR-swizzled in prep
// (quad P <- source quad P^((P>>3)&7), involution) so the octet-strided
// ds_read_b128 pattern is bank-conflict-free. Wog (18 regs) and W1 (8 regs)
// are consume-then-reload register prefetches with a full step of distance.

#define Bn 8192
#define Dn 64
#define CTXn 256
#define Hn 512
#define On 128

#define W2G_SZ (64 * 9 * 512)   // 294912
#define WOG_SZ (64 * 9 * 128)   //  73728
#define WCP_SZ (CTXn * Hn)      // 131072
#define W1C_SZ (Dn * Hn)        //  32768

// S_of(k) = # units with degree < k. Degrees 1..8 have 9 units, 9..63 have 8.
__device__ __forceinline__ int S_of(int k) {
  if (k <= 0) return 0;
  if (k <= 9) return 9 * (k - 1);
  return 72 + 8 * (k - 9);
}

// sorted index p -> original hidden unit h, and its degree k.
__device__ __forceinline__ int perm_of(int p, int* degout) {
  int k, t;
  if (p < 72) { k = p / 9 + 1; t = p - (k - 1) * 9; }
  else        { int pp = p - 72; k = pp / 8 + 9; t = pp - (k - 9) * 8; }
  *degout = k;
  return (k - 1) + 63 * t;
}

// ---------------- prep: padded/masked weight blocks into ws ------------------
// W2g[i][p][d]: step-i group weights, column dimension XOR-swizzled per quad
// (storage quad P holds source quad P^((P>>3)&7); involution). Zero rows for
// p>=c and zero for already-final columns. Wog[i][p][o], WcpT, W1c as before.
__global__ void prep_kernel(const float* __restrict__ W1, const float* __restrict__ Wc,
                            const float* __restrict__ W2, const float* __restrict__ Wo,
                            float* __restrict__ W2g, float* __restrict__ Wog,
                            float* __restrict__ WcpT, float* __restrict__ W1c) {
  int idx = blockIdx.x * 256 + threadIdx.x;
  if (idx < W2G_SZ) {
    int i = idx / 4608, rem = idx - i * 4608;
    int p = rem >> 9, d = rem & 511;
    int P = d >> 2, k = d & 3;
    int q = (((P ^ ((P >> 3) & 7)) << 2) | k);        // source column
    int base = S_of(i + 1), c = S_of(i + 2) - base;   // degree-(i+1) group
    int dq; int hq = perm_of(q, &dq);
    float v = 0.f;
    if (p < c && dq >= i + 1) {            // M2: deg_out >= deg_in (= i+1)
      int dp; int hp = perm_of(base + p, &dp);
      v = W2[hq * Hn + hp];
    }
    W2g[idx] = v;
  } else if (idx < W2G_SZ + WOG_SZ) {
    int jj = idx - W2G_SZ;
    int i = jj / 1152, rem = jj - i * 1152;
    int p = rem >> 7, o = rem & 127;
    int base = S_of(i + 1), c = S_of(i + 2) - base;
    float v = 0.f;
    if (p < c && (o & 63) >= i + 1) {      // Mo: m_o = (o&63)+1 > mh = i+1
      int dp; int hp = perm_of(base + p, &dp);
      v = Wo[o * Hn + hp];
    }
    Wog[jj] = v;
  } else if (idx < W2G_SZ + WOG_SZ + WCP_SZ) {
    int jj = idx - (W2G_SZ + WOG_SZ);
    int cc = jj >> 9, q = jj & 511;
    int dq; int hq = perm_of(q, &dq);
    WcpT[jj] = Wc[hq * CTXn + cc];
  } else if (idx < W2G_SZ + WOG_SZ + WCP_SZ + W1C_SZ) {
    int jj = idx - (W2G_SZ + WOG_SZ + WCP_SZ);
    int i = jj >> 9, q = jj & 511;
    int dq; int hq = perm_of(q, &dq);
    W1c[jj] = (dq >= i + 1) ? W1[hq * Dn + i] : 0.f;   // M1 incl. diagonal
  }
}

// ---------------- main fused kernel ------------------------------------------
__global__ __launch_bounds__(256, 2)
void made_wave_kernel(
    const float* __restrict__ context, const float* __restrict__ WcpT,
    const float* __restrict__ b1,
    const float* __restrict__ W2g, const float* __restrict__ W1c,
    const float* __restrict__ Wog, const float* __restrict__ b2,
    const float* __restrict__ bo, const float* __restrict__ eps,
    float* __restrict__ out) {
  // 9360 floats = 37440 B -> 4 blocks/CU. Overlaid regions:
  //   loop:     w2buf = smem[0..9216) (2x4608), h1b/h2b at 9216/9288
  //   prologue: ctxR = smem[0..2112) ([8][264]), trL = smem[2112..6208)
  __shared__ __align__(16) float smem[9360];
  float* w2buf = smem;
  float (*h1b)[9][2] = (float(*)[9][2])(smem + 9216);
  float (*h2b)[9][2] = (float(*)[9][2])(smem + 9216 + 72);
  float (*ctxR)[264] = (float(*)[264])smem;
  float (*trL)[512]  = (float(*)[512])(smem + 2112);

  int t = threadIdx.x;
  int b0 = blockIdx.x * 8;
  int w = t >> 6, l = t & 63;

  // ================= prologue: ctx GEMM (q-split, 8-row reuse) =============
  #pragma unroll
  for (int r = 0; r < 8; ++r)
    ctxR[r][t] = context[(b0 + r) * CTXn + t];            // coalesced
  __syncthreads();
  {
    int q0 = t, q1 = t + 256;
    int d0, d1; int h0 = perm_of(q0, &d0); int h1 = perm_of(q1, &d1);
    float acc0[8], acc1[8];
    float bias0 = b1[h0], bias1 = b1[h1];
    #pragma unroll
    for (int r = 0; r < 8; ++r) { acc0[r] = bias0; acc1[r] = bias1; }
    const float* wc = WcpT;
    #pragma clang loop unroll(disable)
    for (int c4 = 0; c4 < CTXn / 4; ++c4) {
      float xr[8][4];
      #pragma unroll
      for (int r = 0; r < 8; ++r) {
        float4 x = *(const float4*)&ctxR[r][4 * c4];
        xr[r][0] = x.x; xr[r][1] = x.y; xr[r][2] = x.z; xr[r][3] = x.w;
      }
      #pragma unroll
      for (int k = 0; k < 4; ++k) {
        float w0 = wc[q0];
        float w1 = wc[q1];
        #pragma unroll
        for (int r = 0; r < 8; ++r) {
          acc0[r] = fmaf(xr[r][k], w0, acc0[r]);
          acc1[r] = fmaf(xr[r][k], w1, acc1[r]);
        }
        wc += Hn;
      }
    }
    #pragma unroll
    for (int r = 0; r < 8; ++r) { trL[r][q0] = acc0[r]; trL[r][q1] = acc1[r]; }
  }
  __syncthreads();

  // ============ wave-split reload: lane l owns cols [8l, 8l+8) =============
  int r0 = 2 * w, r1 = 2 * w + 1;
  float2 a1v[8], a2v[8];
  {
    float4 xa = *(const float4*)&trL[r0][8 * l];
    float4 xb = *(const float4*)&trL[r0][8 * l + 4];
    float4 ya = *(const float4*)&trL[r1][8 * l];
    float4 yb = *(const float4*)&trL[r1][8 * l + 4];
    a1v[0] = make_float2(xa.x, ya.x); a1v[1] = make_float2(xa.y, ya.y);
    a1v[2] = make_float2(xa.z, ya.z); a1v[3] = make_float2(xa.w, ya.w);
    a1v[4] = make_float2(xb.x, yb.x); a1v[5] = make_float2(xb.y, yb.y);
    a1v[6] = make_float2(xb.z, yb.z); a1v[7] = make_float2(xb.w, yb.w);
  }
  #pragma unroll
  for (int m = 0; m < 8; ++m) {
    int dd; int hh = perm_of(8 * l + m, &dd);
    float bb = b2[hh];
    a2v[m] = make_float2(bb, bb);
  }
  // finalize-step structure: cols [8l,8l+8) span at most 2 degree groups
  int fA, fB, mS;
  {
    int dd0; perm_of(8 * l, &dd0); fA = dd0 - 1;
    int dd7; perm_of(8 * l + 7, &dd7); fB = dd7 - 1;
    mS = (fB == fA) ? 8 : (S_of(fA + 2) - 8 * l);  // #cols in first group
  }
  __syncthreads();   // all trL reads done; smem region now free for w2buf

  // stage buf0 <- W2g step 0 (plain float4 copy, whole block)
  {
    const float* s = W2g;
    float* d = w2buf;
    *(float4*)(d + 4 * t)        = *(const float4*)(s + 4 * t);
    *(float4*)(d + 4 * t + 1024) = *(const float4*)(s + 4 * t + 1024);
    *(float4*)(d + 4 * t + 2048) = *(const float4*)(s + 4 * t + 2048);
    *(float4*)(d + 4 * t + 3072) = *(const float4*)(s + 4 * t + 3072);
    if (t < 128)
      *(float4*)(d + 4 * t + 4096) = *(const float4*)(s + 4 * t + 4096);
  }
  // register prefetch for step 0: Wog (18), W1 (8)
  float wogv[18];
  #pragma unroll
  for (int p = 0; p < 9; ++p) {
    wogv[2 * p]     = Wog[p * On + l];
    wogv[2 * p + 1] = Wog[p * On + 64 + l];
  }
  float4 w1a = *(const float4*)(W1c + 8 * l);
  float4 w1b = *(const float4*)(W1c + 8 * l + 4);

  // swizzled W2 dword offsets for this lane's two quads
  int Q0 = 2 * l, Q1 = 2 * l + 1;
  int q0d = ((Q0 ^ ((Q0 >> 3) & 7)) << 2);
  int q1d = ((Q1 ^ ((Q1 >> 3) & 7)) << 2);

  float oc00 = bo[l], oc01 = bo[l + 64];
  float oc10 = oc00,  oc11 = oc01;
  float ez0 = eps[(b0 + r0) * Dn + l];
  float ez1 = eps[(b0 + r1) * Dn + l];
  float zv0 = 0.f, zv1 = 0.f, muv0 = 0.f, muv1 = 0.f, scv0 = 0.f, scv1 = 0.f;

  // ============ sequential loop: ONE barrier per step ======================
  #pragma clang loop unroll(disable)
  for (int i = 0; i < Dn; ++i) {
    __syncthreads();  // buf[i&1] staged & prior reads of buf[(i+1)&1] done

    // stage next step's W2 block into the other buffer
    {
      int in = (i < 63) ? i + 1 : 63;
      const float* s = W2g + (size_t)in * 4608;
      float* d = w2buf + ((i + 1) & 1) * 4608;
      *(float4*)(d + 4 * t)        = *(const float4*)(s + 4 * t);
      *(float4*)(d + 4 * t + 1024) = *(const float4*)(s + 4 * t + 1024);
      *(float4*)(d + 4 * t + 2048) = *(const float4*)(s + 4 * t + 2048);
      *(float4*)(d + 4 * t + 3072) = *(const float4*)(s + 4 * t + 3072);
      if (t < 128)
        *(float4*)(d + 4 * t + 4096) = *(const float4*)(s + 4 * t + 4096);
    }

    // E: lane i's cols (i, 64+i) final (oacc through step i-1, in-thread)
    if (l == i) {
      muv0 = oc00; muv1 = oc10;
      float pre0 = oc01, pre1 = oc11;
      scv0 = fmaxf(pre0, 0.f) + __logf(1.f + __expf(-fabsf(pre0)));
      scv1 = fmaxf(pre1, 0.f) + __logf(1.f + __expf(-fabsf(pre1)));
      zv0 = muv0 + scv0 * ez0;
      zv1 = muv1 + scv1 * ez1;
    }
    float z0 = __shfl(zv0, i);             // intra-wave broadcast
    float z1 = __shfl(zv1, i);
    int sb = (i <= 8) ? 9 * i : 8 * i + 8; // S_of(i+1): base of group i
    bool cA = (fA == i), cB = (fB == i);

    // FA: a1 += z_i * W1c[i] (zero-masked, incl. diagonal); group i -> h1b
    if (fB >= i) {
      float wm[8] = {w1a.x, w1a.y, w1a.z, w1a.w, w1b.x, w1b.y, w1b.z, w1b.w};
      #pragma unroll
      for (int m = 0; m < 8; ++m) {
        a1v[m].x = fmaf(wm[m], z0, a1v[m].x);
        a1v[m].y = fmaf(wm[m], z1, a1v[m].y);
      }
      if (cA | cB) {
        int pb = 8 * l - sb;
        #pragma unroll
        for (int m = 0; m < 8; ++m) {
          bool fin = (m < mS) ? cA : cB;
          if (fin)
            *(float2*)&h1b[w][pb + m][0] =
                make_float2(fmaxf(a1v[m].x, 0.f), fmaxf(a1v[m].y, 0.f));
        }
      }
    }
    // reload W1 for next step (full-step latency distance)
    {
      const float* wn = W1c + ((i < 63) ? i + 1 : 63) * Hn + 8 * l;
      w1a = *(const float4*)wn; w1b = *(const float4*)(wn + 4);
    }

    // BC: a2 += W2(LDS, swizzled) . h1b (same-wave program order); -> h2b
    if (fB >= i) {
      const float* wb = w2buf + (i & 1) * 4608;
      #pragma unroll
      for (int p = 0; p < 9; ++p) {
        float4 wa = *(const float4*)(wb + p * 512 + q0d);
        float4 wc = *(const float4*)(wb + p * 512 + q1d);
        float2 h = *(const float2*)&h1b[w][p][0];   // wave-uniform broadcast
        float wm[8] = {wa.x, wa.y, wa.z, wa.w, wc.x, wc.y, wc.z, wc.w};
        #pragma unroll
        for (int m = 0; m < 8; ++m) {
          a2v[m].x = fmaf(wm[m], h.x, a2v[m].x);
          a2v[m].y = fmaf(wm[m], h.y, a2v[m].y);
        }
      }
      if (cA | cB) {
        int pb = 8 * l - sb;
        #pragma unroll
        for (int m = 0; m < 8; ++m) {
          bool fin = (m < mS) ? cA : cB;
          if (fin)
            *(float2*)&h2b[w][pb + m][0] =
                make_float2(fmaxf(a2v[m].x, 0.f), fmaxf(a2v[m].y, 0.f));
        }
      }
    }

    // D: oacc += h2b . wog (registers; Wog zero-padded for cols <= i)
    if (l > i) {
      #pragma unroll
      for (int p = 0; p < 9; ++p) {
        float2 h = *(const float2*)&h2b[w][p][0];
        oc00 = fmaf(h.x, wogv[2 * p], oc00);
        oc01 = fmaf(h.x, wogv[2 * p + 1], oc01);
        oc10 = fmaf(h.y, wogv[2 * p], oc10);
        oc11 = fmaf(h.y, wogv[2 * p + 1], oc11);
      }
    }
    // reload Wog for next step
    {
      const float* wn = Wog + (size_t)((i < 63) ? i + 1 : 63) * 1152;
      #pragma unroll
      for (int p = 0; p < 9; ++p) {
        wogv[2 * p]     = wn[p * On + l];
        wogv[2 * p + 1] = wn[p * On + 64 + l];
      }
    }
  }

  // ================= epilogue: lane l writes col l of z, mu, scale =========
  out[(b0 + r0) * Dn + l] = zv0;
  out[(b0 + r1) * Dn + l] = zv1;
  out[Bn * Dn + (b0 + r0) * Dn + l] = muv0;
  out[Bn * Dn + (b0 + r1) * Dn + l] = muv1;
  out[2 * Bn * Dn + (b0 + r0) * Dn + l] = scv0;
  out[2 * Bn * Dn + (b0 + r1) * Dn + l] = scv1;
}

extern "C" void kernel_launch(void* const* d_in, const int* in_sizes, int n_in,
                              void* d_out, int out_size, void* d_ws, size_t ws_size,
                              hipStream_t stream) {
  const float* context = (const float*)d_in[0];
  const float* eps     = (const float*)d_in[1];
  const float* W1      = (const float*)d_in[2];
  const float* b1      = (const float*)d_in[3];
  const float* Wc      = (const float*)d_in[4];
  const float* W2      = (const float*)d_in[5];
  const float* b2      = (const float*)d_in[6];
  const float* Wo      = (const float*)d_in[7];
  const float* bo      = (const float*)d_in[8];
  float* out = (float*)d_out;

  float* ws   = (float*)d_ws;
  float* W2g  = ws;                 // 294912 floats
  float* Wog  = W2g + W2G_SZ;       //  73728
  float* WcpT = Wog + WOG_SZ;       // 131072
  float* W1c  = WcpT + WCP_SZ;      //  32768
  // total ws use: ~2.1 MB (L2-resident)

  int prep_elems = W2G_SZ + WOG_SZ + WCP_SZ + W1C_SZ;
  prep_kernel<<<(prep_elems + 255) / 256, 256, 0, stream>>>(
      W1, Wc, W2, Wo, W2g, Wog, WcpT, W1c);
  made_wave_kernel<<<Bn / 8, 256, 0, stream>>>(context, WcpT, b1, W2g, W1c,
                                               Wog, b2, bo, eps, out);
}

// Round 10
// 239.195 us; speedup vs baseline: 1.5601x; 1.5601x over previous
//
#include <hip/hip_runtime.h>
#include <math.h>

// MADE autoregressive sampler, incremental-by-degree, v9.
// B=8192, D=64, CTX=256, H=512. Units sorted by degree (mh = h%63+1).
// v9 = v6 structure (Rn=8 rows/block, 3 barriers/step, prefetch-into-barrier)
// with instruction-count attacks:
//  - consumer-packed weights: Wq[i][q][12] = {9x W2, W1, pad2} -> 3 b128/unit
//    with immediate offsets; Woq[i][j][20] = {9 colA, pad, 9 colB, pad} ->
//    5 b128/colpair. Kills v6's ~114 addressing insts + 27 scalar loads/step.
//  - float2 row-pairs (ext_vector_type) -> v_pk_fma_f32 packed-f32 math.
//  - wave-uniform skip of finalized units (readfirstlane'd per-wave bound).
//  - permuted biases b1p/b2p (no perm_of in hot kernel).

typedef float f2 __attribute__((ext_vector_type(2)));

#define Bn 8192
#define Dn 64
#define CTXn 256
#define Hn 512
#define On 128
#define Rn 8

#define WQ_SZ  (64 * 512 * 12)   // 393216
#define WOQ_SZ (64 * 64 * 20)    //  81920
#define WCP_SZ (CTXn * Hn)       // 131072

// S_of(k) = # units with degree < k. Degrees 1..8 have 9 units, 9..63 have 8.
__device__ __forceinline__ int S_of(int k) {
  if (k <= 0) return 0;
  if (k <= 9) return 9 * (k - 1);
  return 72 + 8 * (k - 9);
}
// sorted index p -> original hidden unit h, and its degree k.
__device__ __forceinline__ int perm_of(int p, int* degout) {
  int k, t;
  if (p < 72) { k = p / 9 + 1; t = p - (k - 1) * 9; }
  else        { int pp = p - 72; k = pp / 8 + 9; t = pp - (k - 9) * 8; }
  *degout = k;
  return (k - 1) + 63 * t;
}

// ---------------- prep ------------------------------------------------------
// Wq[i][q][e]: e<9 -> W2 from group-i unit e into q (M2, zero-padded);
//              e==9 -> W1 col i into q (M1 incl diagonal); e=10,11 pad.
// Woq[i][j][e]: e<9 -> Wog p=e -> col j; e==9 pad; 10..18 -> p=e-10 col j+64;
//              e==19 pad. (Mo: col final mask j >= i+1.)
// WcpT[c][q], b1p[q], b2p[q].
__global__ void prep_kernel(const float* __restrict__ W1, const float* __restrict__ Wc,
                            const float* __restrict__ W2, const float* __restrict__ Wo,
                            const float* __restrict__ b1, const float* __restrict__ b2,
                            float* __restrict__ Wq, float* __restrict__ Woq,
                            float* __restrict__ WcpT, float* __restrict__ b1p,
                            float* __restrict__ b2p) {
  int idx = blockIdx.x * 256 + threadIdx.x;
  if (idx < WQ_SZ) {
    int i = idx / 6144, rem = idx - i * 6144;
    int q = rem / 12, e = rem - q * 12;
    int sb = (i < 8) ? 9 * i : 8 * i + 8;          // S_of(i+1)
    int c  = (i == 63) ? 0 : ((i < 8) ? 9 : 8);
    int dq; int hq = perm_of(q, &dq);
    float v = 0.f;
    if (e < 9) {
      if (e < c && dq >= i + 1) {                  // M2: deg_out >= i+1
        int dp; int hp = perm_of(sb + e, &dp);
        v = W2[hq * Hn + hp];
      }
    } else if (e == 9) {
      if (dq >= i + 1) v = W1[hq * Dn + i];        // M1 incl diagonal
    }
    Wq[idx] = v;
  } else if (idx < WQ_SZ + WOQ_SZ) {
    int jj = idx - WQ_SZ;
    int i = jj / 1280, rem = jj - i * 1280;
    int j = rem / 20, e = rem - j * 20;
    int sb = (i < 8) ? 9 * i : 8 * i + 8;
    int c  = (i == 63) ? 0 : ((i < 8) ? 9 : 8);
    float v = 0.f;
    int p = -1, o = 0;
    if (e < 9)                { p = e;      o = j; }
    else if (e >= 10 && e < 19) { p = e - 10; o = j + 64; }
    if (p >= 0 && p < c && j >= i + 1) {           // Mo: (o&63) >= i+1
      int dp; int hp = perm_of(sb + p, &dp);
      v = Wo[o * Hn + hp];
    }
    Woq[jj] = v;
  } else if (idx < WQ_SZ + WOQ_SZ + WCP_SZ) {
    int jj = idx - (WQ_SZ + WOQ_SZ);
    int cc = jj >> 9, q = jj & 511;
    int dq; int hq = perm_of(q, &dq);
    WcpT[jj] = Wc[hq * CTXn + cc];
  } else if (idx < WQ_SZ + WOQ_SZ + WCP_SZ + 512) {
    int q = idx - (WQ_SZ + WOQ_SZ + WCP_SZ);
    int dq; int hq = perm_of(q, &dq);
    b1p[q] = b1[hq];
  } else if (idx < WQ_SZ + WOQ_SZ + WCP_SZ + 1024) {
    int q = idx - (WQ_SZ + WOQ_SZ + WCP_SZ + 512);
    int dq; int hq = perm_of(q, &dq);
    b2p[q] = b2[hq];
  }
}

// ---------------- main fused kernel ------------------------------------------
__global__ __launch_bounds__(256, 4)
void made_pk_kernel(
    const float* __restrict__ context, const float* __restrict__ WcpT,
    const float* __restrict__ b1p,
    const float* __restrict__ Wq, const float* __restrict__ Woq,
    const float* __restrict__ b2p, const float* __restrict__ bo,
    const float* __restrict__ eps, float* __restrict__ out) {
  __shared__ __align__(16) float ctxR[8][264];
  __shared__ __align__(16) float zcur[8];
  __shared__ __align__(16) float h1g[9][8];
  __shared__ __align__(16) float h2g[9][8];

  int t = threadIdx.x;
  int b0 = blockIdx.x * Rn;
  int rp = t >> 6, l = t & 63;           // wave rp owns rows 2rp, 2rp+1; col-pair l
  int q0 = t, q1 = t + 256;              // owned sorted units

  int g0 = ((q0 < 72) ? q0 / 9 + 1 : (q0 - 72) / 8 + 9) - 1;   // finalize steps
  int g1 = ((q1 - 72) / 8 + 9) - 1;
  int qm = t | 63;                        // wave-uniform max index
  int gm0s = __builtin_amdgcn_readfirstlane(
      ((qm < 72) ? qm / 9 + 1 : (qm - 72) / 8 + 9) - 1);
  int gm1s = __builtin_amdgcn_readfirstlane(((qm + 256 - 72) / 8 + 9) - 1);

  // ---- stage ctx ----
  #pragma unroll
  for (int r = 0; r < 8; ++r)
    ctxR[r][t] = context[(b0 + r) * CTXn + t];
  __syncthreads();

  // ---- ctx GEMM (v6-proven) ----
  float acc0[8], acc1[8];
  {
    float bias0 = b1p[q0], bias1 = b1p[q1];
    #pragma unroll
    for (int r = 0; r < 8; ++r) { acc0[r] = bias0; acc1[r] = bias1; }
  }
  {
    const float* wc = WcpT;
    #pragma clang loop unroll(disable)
    for (int c4 = 0; c4 < CTXn / 4; ++c4) {
      float xr[8][4];
      #pragma unroll
      for (int r = 0; r < 8; ++r) {
        float4 x = *(const float4*)&ctxR[r][4 * c4];
        xr[r][0] = x.x; xr[r][1] = x.y; xr[r][2] = x.z; xr[r][3] = x.w;
      }
      #pragma unroll
      for (int k = 0; k < 4; ++k) {
        float w0 = wc[q0], w1 = wc[q1];
        #pragma unroll
        for (int r = 0; r < 8; ++r) {
          acc0[r] = fmaf(xr[r][k], w0, acc0[r]);
          acc1[r] = fmaf(xr[r][k], w1, acc1[r]);
        }
        wc += Hn;
      }
    }
  }

  // ---- pack state into float2 row-pairs ----
  f2 a10[4], a11[4], a20[4], a21[4];
  #pragma unroll
  for (int r2 = 0; r2 < 4; ++r2) {
    a10[r2] = (f2){acc0[2 * r2], acc0[2 * r2 + 1]};
    a11[r2] = (f2){acc1[2 * r2], acc1[2 * r2 + 1]};
  }
  {
    float bb0 = b2p[q0], bb1 = b2p[q1];
    #pragma unroll
    for (int r2 = 0; r2 < 4; ++r2) {
      a20[r2] = (f2){bb0, bb0};
      a21[r2] = (f2){bb1, bb1};
    }
  }
  f2 ocA = (f2){bo[l], bo[l]};           // col l, rows (2rp, 2rp+1)
  f2 ocB = (f2){bo[l + 64], bo[l + 64]};
  f2 ez2 = (f2){eps[(b0 + 2 * rp) * Dn + l], eps[(b0 + 2 * rp + 1) * Dn + l]};
  f2 zs = (f2){0.f, 0.f}, mus = zs, scs = zs;

  const float* wq0p = Wq + (size_t)q0 * 12;
  const float* wq1p = Wq + (size_t)q1 * 12;
  const float* wopp = Woq + (size_t)l * 20;

  // ---- sequential loop: 3 barriers/step (must stay rolled) ----
  #pragma clang loop unroll(disable)
  for (int i = 0; i < Dn; ++i) {
    // E: this thread's cols (l, l+64) final when l == i (oacc through D(i-1))
    if (l == i) {
      f2 pre = ocB;
      float sx = fmaxf(pre.x, 0.f) + __logf(1.f + __expf(-fabsf(pre.x)));
      float sy = fmaxf(pre.y, 0.f) + __logf(1.f + __expf(-fabsf(pre.y)));
      f2 sc = (f2){sx, sy};
      f2 z = ocA + sc * ez2;
      *(f2*)&zcur[2 * rp] = z;
      zs = z; mus = ocA; scs = sc;
    }
    __syncthreads();                               // bar1: z published

    int sb = (i < 8) ? 9 * i : 8 * i + 8;          // group-i base
    bool liveB = (i <= gm1s);                      // wave-uniform
    bool liveA = (i <= gm0s);
    float4 A1c0, A1c1, A1c2, A0c0, A0c1, A0c2;
    if (liveB) {
      const float4* a4 = (const float4*)wq1p;      // 3 b128, imm offsets
      A1c0 = a4[0]; A1c1 = a4[1]; A1c2 = a4[2];
      if (liveA) {
        const float4* b4 = (const float4*)wq0p;
        A0c0 = b4[0]; A0c1 = b4[1]; A0c2 = b4[2];
      }
      float4 za = *(const float4*)&zcur[0];
      float4 zb = *(const float4*)&zcur[4];
      f2 zc0 = (f2){za.x, za.y}, zc1 = (f2){za.z, za.w};
      f2 zc2 = (f2){zb.x, zb.y}, zc3 = (f2){zb.z, zb.w};
      // FA unit1: a1 += z_i * W1 (slot [9] = chunk2.y), publish if finalizing
      {
        f2 wv = (f2){A1c2.y, A1c2.y};
        a11[0] += wv * zc0; a11[1] += wv * zc1;
        a11[2] += wv * zc2; a11[3] += wv * zc3;
        if (g1 == i) {
          int pp = q1 - sb;
          float4 h0 = {fmaxf(a11[0].x, 0.f), fmaxf(a11[0].y, 0.f),
                       fmaxf(a11[1].x, 0.f), fmaxf(a11[1].y, 0.f)};
          float4 h1_ = {fmaxf(a11[2].x, 0.f), fmaxf(a11[2].y, 0.f),
                        fmaxf(a11[3].x, 0.f), fmaxf(a11[3].y, 0.f)};
          *(float4*)&h1g[pp][0] = h0; *(float4*)&h1g[pp][4] = h1_;
        }
      }
      if (liveA) {
        f2 wv = (f2){A0c2.y, A0c2.y};
        a10[0] += wv * zc0; a10[1] += wv * zc1;
        a10[2] += wv * zc2; a10[3] += wv * zc3;
        if (g0 == i) {
          int pp = q0 - sb;
          float4 h0 = {fmaxf(a10[0].x, 0.f), fmaxf(a10[0].y, 0.f),
                       fmaxf(a10[1].x, 0.f), fmaxf(a10[1].y, 0.f)};
          float4 h1_ = {fmaxf(a10[2].x, 0.f), fmaxf(a10[2].y, 0.f),
                        fmaxf(a10[3].x, 0.f), fmaxf(a10[3].y, 0.f)};
          *(float4*)&h1g[pp][0] = h0; *(float4*)&h1g[pp][4] = h1_;
        }
      }
    }
    __syncthreads();                               // bar2: h1 published

    // Woq prefetch (used in D after bar3 -> drains at an anyway-barrier)
    const float4* w4 = (const float4*)wopp;
    float4 B0 = w4[0], B1 = w4[1], B2 = w4[2], B3 = w4[3], B4 = w4[4];

    if (liveB) {
      float wA1[9] = {A1c0.x, A1c0.y, A1c0.z, A1c0.w,
                      A1c1.x, A1c1.y, A1c1.z, A1c1.w, A1c2.x};
      if (liveA) {
        float wA0[9] = {A0c0.x, A0c0.y, A0c0.z, A0c0.w,
                        A0c1.x, A0c1.y, A0c1.z, A0c1.w, A0c2.x};
        #pragma unroll
        for (int p = 0; p < 9; ++p) {
          float4 ha = *(const float4*)&h1g[p][0];
          float4 hb = *(const float4*)&h1g[p][4];
          f2 h0 = (f2){ha.x, ha.y}, h1_ = (f2){ha.z, ha.w};
          f2 h2_ = (f2){hb.x, hb.y}, h3 = (f2){hb.z, hb.w};
          f2 wv1 = (f2){wA1[p], wA1[p]};
          f2 wv0 = (f2){wA0[p], wA0[p]};
          a21[0] += wv1 * h0; a21[1] += wv1 * h1_;
          a21[2] += wv1 * h2_; a21[3] += wv1 * h3;
          a20[0] += wv0 * h0; a20[1] += wv0 * h1_;
          a20[2] += wv0 * h2_; a20[3] += wv0 * h3;
        }
      } else {
        #pragma unroll
        for (int p = 0; p < 9; ++p) {
          float4 ha = *(const float4*)&h1g[p][0];
          float4 hb = *(const float4*)&h1g[p][4];
          f2 h0 = (f2){ha.x, ha.y}, h1_ = (f2){ha.z, ha.w};
          f2 h2_ = (f2){hb.x, hb.y}, h3 = (f2){hb.z, hb.w};
          f2 wv1 = (f2){wA1[p], wA1[p]};
          a21[0] += wv1 * h0; a21[1] += wv1 * h1_;
          a21[2] += wv1 * h2_; a21[3] += wv1 * h3;
        }
      }
      if (g1 == i) {
        int pp = q1 - sb;
        float4 h0 = {fmaxf(a21[0].x, 0.f), fmaxf(a21[0].y, 0.f),
                     fmaxf(a21[1].x, 0.f), fmaxf(a21[1].y, 0.f)};
        float4 h1_ = {fmaxf(a21[2].x, 0.f), fmaxf(a21[2].y, 0.f),
                      fmaxf(a21[3].x, 0.f), fmaxf(a21[3].y, 0.f)};
        *(float4*)&h2g[pp][0] = h0; *(float4*)&h2g[pp][4] = h1_;
      }
      if (liveA && g0 == i) {
        int pp = q0 - sb;
        float4 h0 = {fmaxf(a20[0].x, 0.f), fmaxf(a20[0].y, 0.f),
                     fmaxf(a20[1].x, 0.f), fmaxf(a20[1].y, 0.f)};
        float4 h1_ = {fmaxf(a20[2].x, 0.f), fmaxf(a20[2].y, 0.f),
                      fmaxf(a20[3].x, 0.f), fmaxf(a20[3].y, 0.f)};
        *(float4*)&h2g[pp][0] = h0; *(float4*)&h2g[pp][4] = h1_;
      }
    }
    __syncthreads();                               // bar3: h2 published

    // D: oacc += h2 . Wog (zero-padded for cols <= i -> no branch)
    {
      float wBa[9] = {B0.x, B0.y, B0.z, B0.w, B1.x, B1.y, B1.z, B1.w, B2.x};
      float wBb[9] = {B2.z, B2.w, B3.x, B3.y, B3.z, B3.w, B4.x, B4.y, B4.z};
      #pragma unroll
      for (int p = 0; p < 9; ++p) {
        f2 h = *(const f2*)&h2g[p][2 * rp];        // b64 broadcast (wave-uniform)
        ocA += (f2){wBa[p], wBa[p]} * h;
        ocB += (f2){wBb[p], wBb[p]} * h;
      }
    }
    wq0p += 6144; wq1p += 6144; wopp += 1280;
  }

  // ---- epilogue: thread (rp,l) holds z/mu/sc for rows 2rp,2rp+1 col l ----
  out[(b0 + 2 * rp) * Dn + l] = zs.x;
  out[(b0 + 2 * rp + 1) * Dn + l] = zs.y;
  out[Bn * Dn + (b0 + 2 * rp) * Dn + l] = mus.x;
  out[Bn * Dn + (b0 + 2 * rp + 1) * Dn + l] = mus.y;
  out[2 * Bn * Dn + (b0 + 2 * rp) * Dn + l] = scs.x;
  out[2 * Bn * Dn + (b0 + 2 * rp + 1) * Dn + l] = scs.y;
}

extern "C" void kernel_launch(void* const* d_in, const int* in_sizes, int n_in,
                              void* d_out, int out_size, void* d_ws, size_t ws_size,
                              hipStream_t stream) {
  const float* context = (const float*)d_in[0];
  const float* eps     = (const float*)d_in[1];
  const float* W1      = (const float*)d_in[2];
  const float* b1      = (const float*)d_in[3];
  const float* Wc      = (const float*)d_in[4];
  const float* W2      = (const float*)d_in[5];
  const float* b2      = (const float*)d_in[6];
  const float* Wo      = (const float*)d_in[7];
  const float* bo      = (const float*)d_in[8];
  float* out = (float*)d_out;

  float* ws   = (float*)d_ws;
  float* Wq   = ws;                        // 393216 floats
  float* Woq  = Wq + WQ_SZ;                //  81920
  float* WcpT = Woq + WOQ_SZ;              // 131072
  float* b1p  = WcpT + WCP_SZ;             //    512
  float* b2p  = b1p + 512;                 //    512
  // total ws use: ~2.4 MB (L2-resident)

  int prep_elems = WQ_SZ + WOQ_SZ + WCP_SZ + 1024;
  prep_kernel<<<(prep_elems + 255) / 256, 256, 0, stream>>>(
      W1, Wc, W2, Wo, b1, b2, Wq, Woq, WcpT, b1p, b2p);
  made_pk_kernel<<<Bn / Rn, 256, 0, stream>>>(context, WcpT, b1p, Wq, Woq,
                                              b2p, bo, eps, out);
}